// Round 2
// baseline (7024.258 us; speedup 1.0000x reference)
//
#include <hip/hip_runtime.h>

#define NB 64      // batch
#define NT 64      // time
#define ND 1024    // DETER
#define NH 1024    // HID
#define NE 1536    // EMBED
#define NA 6       // ACT
#define NSC 1024   // STOCH*CLASSES
#define GIN 1030   // GRU_IN
#define W1STR 2560 // post_w1 row stride (ND+NE)
#define EPS 1e-5f

typedef float f4v __attribute__((ext_vector_type(4)));

// ---- workspace layout (float offsets) ----
#define O_EPRE   0u            // [T][NH][NB]  epre, then phT[t] in-place, then k3 ph1
#define O_HHIST  4194304u      // [T][ND][NB]
#define O_LHIST  8388608u      // [T][NSC][NB] (post logits, [t][j][b])
#define O_EMBT   4194304u      // overlay on HHIST+LHIST pre-scan: [T][NE][NB]
#define O_BAR    12582912u     // u32[0]=epoch, u32[32]=arrive counter
#define O_FLAGS  12582976u     // (legacy, unused)
#define O_GMAX   12812288u     // u64[32][NB] packed argmax keys
#define O_ZIDX   12816384u     // int[T][32][NB]
#define O_ACTT   12947456u     // [T][NA][NB]
#define O_KEEPT  12972032u     // [T][NB]
#define O_PSTAT  12976128u     // [T][NB][2] prior LN stats (k3)

// out layout (floats)
#define OUT_LATENT 0u
#define OUT_HSEQ   8388608u
#define OUT_POST   12582912u
#define OUT_PRIOR  16777216u

// ---- coherence-point bypass ops (agent scope, relaxed) ----
__device__ __forceinline__ float gload(const float* p) {
    return __uint_as_float(__hip_atomic_load((const unsigned int*)p,
                __ATOMIC_RELAXED, __HIP_MEMORY_SCOPE_AGENT));
}
__device__ __forceinline__ unsigned long long gload64(const unsigned long long* p) {
    return __hip_atomic_load(p, __ATOMIC_RELAXED, __HIP_MEMORY_SCOPE_AGENT);
}
__device__ __forceinline__ void gstore64(unsigned long long* p, unsigned long long v) {
    __hip_atomic_store(p, v, __ATOMIC_RELAXED, __HIP_MEMORY_SCOPE_AGENT);
}
__device__ __forceinline__ unsigned int gload32(const unsigned int* p) {
    return __hip_atomic_load(p, __ATOMIC_RELAXED, __HIP_MEMORY_SCOPE_AGENT);
}
__device__ __forceinline__ void gstore32(unsigned int* p, unsigned int v) {
    __hip_atomic_store(p, v, __ATOMIC_RELAXED, __HIP_MEMORY_SCOPE_AGENT);
}
// 16B L2-bypass store (device-coherent): lands at L3, visible to all XCDs
// after vmcnt(0)+flag release. Safe only for lines with no valid L2 copies
// anywhere (t-indexed, first touch) — holds for hhist[t]/epre[t] writes.
__device__ __forceinline__ void gstore128(float* p, f4v v) {
    asm volatile("global_store_dwordx4 %0, %1, off sc0 sc1"
                 :: "v"(p), "v"(v) : "memory");
}

// =================== K0: transposes + zero-init ===================
__global__ void k0_prep(const float* __restrict__ embeds,
                        const float* __restrict__ actions,
                        const int* __restrict__ isfirst,
                        float* __restrict__ ws)
{
    int blk = blockIdx.x, tid = threadIdx.x;
    int rr = tid >> 6, ln = tid & 63;
    if (blk < 1536) {
        // embeds (B,T,E) -> emb_T [t][e][b]
        int t = blk / 24, et = blk % 24, e0 = et * 64;
        __shared__ float tile[64][65];
        for (int q = 0; q < 16; ++q) {
            int b = q * 4 + rr;
            tile[b][ln] = embeds[((size_t)b * NT + t) * NE + e0 + ln];
        }
        __syncthreads();
        float* embT = ws + O_EMBT + (size_t)t * NE * NB;
        for (int q = 0; q < 16; ++q) {
            int e = q * 4 + rr;
            embT[(size_t)(e0 + e) * NB + ln] = tile[ln][e];
        }
    } else if (blk == 1536) {
        for (int i = tid; i < NT * NA * NB; i += 256) {
            int t = i / (NA * NB); int rem = i % (NA * NB);
            int a = rem / NB; int b = rem % NB;
            ws[O_ACTT + i] = actions[((size_t)b * NT + t) * NA + a];
        }
        for (int i = tid; i < NT * NB; i += 256) {
            int t = i / NB, b = i % NB;
            ws[O_KEEPT + i] = 1.f - (float)isfirst[(size_t)b * NT + t];
        }
    } else {
        if (tid < 64) ((unsigned int*)(ws + O_BAR))[tid] = 0u;   // epoch + arrive
        for (int i = tid; i < 256 * 32; i += 256)
            ((unsigned int*)(ws + O_FLAGS))[i] = 0u;
        for (int i = tid; i < NT * NB * 2; i += 256)
            ws[O_PSTAT + i] = 0.f;
    }
}

// =================== K1: E_pre = emb @ post_w1[:,1024:]^T ===================
__global__ __launch_bounds__(256) void k1_epre(const float* __restrict__ qw1,
                                               float* __restrict__ ws)
{
    int blk = blockIdx.x;
    int t = blk >> 6, kg = blk & 63, k0 = kg * 16;
    int tid = threadIdx.x, w = tid >> 6, lane = tid & 63;
    const float* embT = ws + O_EMBT + (size_t)t * NE * NB;
    float acc[16];
#pragma unroll
    for (int i = 0; i < 16; ++i) acc[i] = 0.f;
    int e0 = w * 384;
    for (int e = e0; e < e0 + 384; e += 4) {
        float ev0 = embT[(size_t)(e + 0) * NB + lane];
        float ev1 = embT[(size_t)(e + 1) * NB + lane];
        float ev2 = embT[(size_t)(e + 2) * NB + lane];
        float ev3 = embT[(size_t)(e + 3) * NB + lane];
#pragma unroll
        for (int kk = 0; kk < 16; ++kk) {
            float4 wv = *(const float4*)&qw1[(size_t)(k0 + kk) * W1STR + ND + e];
            acc[kk] = fmaf(wv.x, ev0, acc[kk]);
            acc[kk] = fmaf(wv.y, ev1, acc[kk]);
            acc[kk] = fmaf(wv.z, ev2, acc[kk]);
            acc[kk] = fmaf(wv.w, ev3, acc[kk]);
        }
    }
    __shared__ float red[4][16][64];
#pragma unroll
    for (int kk = 0; kk < 16; ++kk) red[w][kk][lane] = acc[kk];
    __syncthreads();
    float* epre = ws + O_EPRE + (size_t)t * NH * NB;
    for (int q = 0; q < 4; ++q) {
        int slot = tid + q * 256;
        int kk = slot >> 6, b = slot & 63;
        float v = red[0][kk][b] + red[1][kk][b] + red[2][kk][b] + red[3][kk][b];
        epre[(size_t)(k0 + kk) * NB + b] = v;
    }
}

// =================== K2: the scan ===================
// 256 blocks x 1024 threads (16 waves/CU). Whh in LDS.
// Grid barrier: monotonic arrival counter (1 atomicAdd/block/epoch, no
// leader flag sweep) + sparse epoch polling — O(1) coherence lines per
// arrival instead of the multi-GB spin traffic of the flag-sweep design.
__global__ __launch_bounds__(1024)
void k2_scan(const float* __restrict__ Wih, const float* __restrict__ Whh,
             const float* __restrict__ bih, const float* __restrict__ bhh,
             const float* __restrict__ qw1, const float* __restrict__ qb1,
             const float* __restrict__ qg,  const float* __restrict__ qbe,
             const float* __restrict__ qw2, const float* __restrict__ qb2,
             float* __restrict__ ws)
{
    const int blk = blockIdx.x, tid = threadIdx.x;
    const int w = tid >> 6, lane = tid & 63;       // w in [0,16)
    const int d0 = blk * 4;                        // owned 4 dims
    const int dd = (tid >> 6) & 3, bb = tid & 63;  // finalize mapping (tid<256)

    float* hhist = ws + O_HHIST;
    float* lhist = ws + O_LHIST;
    float* epre  = ws + O_EPRE;          // also phT[t] in-place
    unsigned int* epoch  = (unsigned int*)(ws + O_BAR);
    unsigned int* arrive = (unsigned int*)(ws + O_BAR) + 32;   // separate line
    unsigned long long* gmax = (unsigned long long*)(ws + O_GMAX);
    int* zidx = (int*)(ws + O_ZIDX);
    const float* actT  = ws + O_ACTT;
    const float* keepT = ws + O_KEEPT;

    __shared__ __align__(16) float sWhh[12][1024];   // 48KB: rows gate*4+dd
    __shared__ float sRed[16][12][64];                // 48KB
    __shared__ float sV[4][64];                       // 1KB staging for vec stores
    __shared__ float smean[64], srstd[64];
    __shared__ unsigned long long pkst[4][64];        // 2KB
    __shared__ float sGx[3][4][64];                   // 3KB gate partials
    __shared__ unsigned int zcS[8][64];               // 2KB packed z indices

    // ---- stage Whh slice once (coalesced float4 per row) ----
    for (int i4 = tid; i4 < 12 * 256; i4 += 1024) {
        int r = i4 >> 8, k4 = (i4 & 255) * 4;
        int row = (r >> 2) * 1024 + d0 + (r & 3);
        *(float4*)&sWhh[r][k4] = *(const float4*)&Whh[(size_t)row * ND + k4];
    }
    __syncthreads();

    unsigned int ep = 0;

#define GRID_BARRIER()  do { \
        ++ep; \
        asm volatile("s_waitcnt vmcnt(0) lgkmcnt(0)" ::: "memory"); \
        __syncthreads(); \
        if (blk == 0) { \
            if (tid == 0) { \
                while (gload32(arrive) < 255u * ep) __builtin_amdgcn_s_sleep(2); \
                gstore32(epoch, ep); \
            } \
        } else { \
            if (tid == 0) { \
                __hip_atomic_fetch_add(arrive, 1u, __ATOMIC_RELAXED, \
                                       __HIP_MEMORY_SCOPE_AGENT); \
                while (gload32(epoch) < ep) __builtin_amdgcn_s_sleep(8); \
            } \
        } \
        __syncthreads(); \
    } while (0)

    for (int t = 0; t < NT; ++t) {
        // ---------------- PHASE A: GRU -> h_new ----------------
        {
            // preamble: wave 0 unpacks gmax -> zcS (overlaps with Whh on waves 1-15)
            if (t > 0 && tid < 64) {
                unsigned int packed[8];
#pragma unroll
                for (int j = 0; j < 8; ++j) packed[j] = 0u;
                unsigned long long pkv[16];
#pragma unroll
                for (int h2 = 0; h2 < 2; ++h2) {
#pragma unroll
                    for (int g = 0; g < 16; ++g)
                        pkv[g] = gload64(&gmax[(h2 * 16 + g) * 64 + tid]);
#pragma unroll
                    for (int g = 0; g < 16; ++g) {
                        int gg = h2 * 16 + g;
                        unsigned int c = 31u - ((unsigned int)pkv[g] & 31u);
                        packed[gg >> 2] |= c << ((gg & 3) * 8);
                        if (blk == 0)
                            zidx[(t - 1) * 32 * NB + gg * NB + tid] = (int)c;
                    }
                }
#pragma unroll
                for (int j = 0; j < 8; ++j) zcS[j][tid] = packed[j];
            }

            float acc[12];
#pragma unroll
            for (int r = 0; r < 12; ++r) acc[r] = 0.f;
            if (t > 0) {
                const float* hp = hhist + (size_t)(t - 1) * ND * NB;  // L2-warm normal reads
                int base = w * 64;
                for (int kt = 0; kt < 64; kt += 16) {
                    float hbuf[16];
#pragma unroll
                    for (int j = 0; j < 16; ++j)
                        hbuf[j] = hp[(size_t)(base + kt + j) * NB + lane];
#pragma unroll
                    for (int j4 = 0; j4 < 16; j4 += 4) {
                        int k = base + kt + j4;
#pragma unroll
                        for (int r = 0; r < 12; ++r) {
                            float4 wv = *(const float4*)&sWhh[r][k];   // LDS broadcast
                            acc[r] = fmaf(wv.x, hbuf[j4 + 0], acc[r]);
                            acc[r] = fmaf(wv.y, hbuf[j4 + 1], acc[r]);
                            acc[r] = fmaf(wv.z, hbuf[j4 + 2], acc[r]);
                            acc[r] = fmaf(wv.w, hbuf[j4 + 3], acc[r]);
                        }
                    }
                }
            }
#pragma unroll
            for (int r = 0; r < 12; ++r) sRed[w][r][lane] = acc[r];
            __syncthreads();
            // gate-parallel z/act gather (tid<768: gate = tid>>8)
            if (tid < 768) {
                int g3 = tid >> 8, dd3 = (tid >> 6) & 3, bb3 = tid & 63;
                int d = d0 + dd3;
                const float* Wrow = Wih + (size_t)(g3 * 1024 + d) * GIN;
                float keep = keepT[t * NB + bb3];
                float gx = bih[g3 * 1024 + d];
                if (t > 0) {
                    unsigned int zcb[8];
#pragma unroll
                    for (int j = 0; j < 8; ++j) zcb[j] = zcS[j][bb3];
                    float s = 0.f;
#pragma unroll 8
                    for (int g = 0; g < 32; ++g) {
                        int c = (int)((zcb[g >> 2] >> ((g & 3) * 8)) & 31u);
                        s += Wrow[g * 32 + c];
                    }
                    gx = fmaf(keep, s, gx);
                }
#pragma unroll
                for (int a = 0; a < NA; ++a)
                    gx = fmaf(Wrow[ND + a], actT[(t * NA + a) * NB + bb3], gx);
                sGx[g3][dd3][bb3] = gx;
            }
            __syncthreads();
            if (tid < 256) {
                int d = d0 + dd;
                float keep = keepT[t * NB + bb];
                float gh0 = 0.f, gh1 = 0.f, gh2 = 0.f;
#pragma unroll
                for (int ww = 0; ww < 16; ++ww) {
                    gh0 += sRed[ww][dd + 0][bb];
                    gh1 += sRed[ww][dd + 4][bb];
                    gh2 += sRed[ww][dd + 8][bb];
                }
                float ghr = fmaf(keep, gh0, bhh[d]);
                float ghz = fmaf(keep, gh1, bhh[1024 + d]);
                float ghn = fmaf(keep, gh2, bhh[2048 + d]);
                float gxr = sGx[0][dd][bb], gxz = sGx[1][dd][bb], gxn = sGx[2][dd][bb];
                float r = 1.f / (1.f + __expf(-(gxr + ghr)));
                float u = 1.f / (1.f + __expf(-(gxz + ghz)));
                float n = tanhf(gxn + r * ghn);
                float hprevm = 0.f;
                if (t > 0)
                    hprevm = keep * hhist[((size_t)(t - 1) * ND + d) * NB + bb];  // L2-warm
                sV[dd][bb] = (1.f - u) * n + u * hprevm;
            }
            __syncthreads();
            if (tid < 64) {   // vectorized bypass store: 4 rows x 16 float4
                int d2 = tid >> 4, bq = (tid & 15) * 4;
                f4v v = { sV[d2][bq], sV[d2][bq + 1], sV[d2][bq + 2], sV[d2][bq + 3] };
                gstore128(&hhist[((size_t)t * ND + d0 + d2) * NB + bq], v);
            }
        }
        // -------- S1 --------
        GRID_BARRIER();
        // -------- PHASE B: post w1 (h part) + E_pre -> phT (in epre[t]) --------
        {
            const float* hrow = hhist + (size_t)t * ND * NB;   // normal (first touch fresh)
            float eprev = 0.f;
            if (tid < 256)   // issue bypass read early (hidden under FMA loop)
                eprev = gload(&epre[((size_t)t * NH + d0 + dd) * NB + bb]);
            float acc4[4] = {0.f, 0.f, 0.f, 0.f};
            int base = w * 64;
            for (int kt = 0; kt < 64; kt += 16) {
                float hbuf[16];
#pragma unroll
                for (int j = 0; j < 16; ++j)
                    hbuf[j] = hrow[(size_t)(base + kt + j) * NB + lane];
#pragma unroll
                for (int j4 = 0; j4 < 16; j4 += 4) {
                    int k = base + kt + j4;
#pragma unroll
                    for (int rr = 0; rr < 4; ++rr) {
                        float4 wv = *(const float4*)&qw1[(size_t)(d0 + rr) * W1STR + k];
                        acc4[rr] = fmaf(wv.x, hbuf[j4 + 0], acc4[rr]);
                        acc4[rr] = fmaf(wv.y, hbuf[j4 + 1], acc4[rr]);
                        acc4[rr] = fmaf(wv.z, hbuf[j4 + 2], acc4[rr]);
                        acc4[rr] = fmaf(wv.w, hbuf[j4 + 3], acc4[rr]);
                    }
                }
            }
#pragma unroll
            for (int rr = 0; rr < 4; ++rr) sRed[w][rr][lane] = acc4[rr];
            if (blk == 0 && tid >= 768) {   // reset argmax accumulators (waves 12-15)
                for (int i = tid - 768; i < 2048; i += 256) gstore64(&gmax[i], 0ull);
            }
            __syncthreads();
            if (tid < 256) {
                float s = 0.f;
#pragma unroll
                for (int ww = 0; ww < 16; ++ww) s += sRed[ww][dd][bb];
                sV[dd][bb] = s + qb1[d0 + dd] + eprev;
            }
            __syncthreads();
            if (tid < 64) {
                int d2 = tid >> 4, bq = (tid & 15) * 4;
                f4v v = { sV[d2][bq], sV[d2][bq + 1], sV[d2][bq + 2], sV[d2][bq + 3] };
                gstore128(&epre[((size_t)t * NH + d0 + d2) * NB + bq], v);
            }
        }
        // -------- S2 --------
        GRID_BARRIER();
        // ---------------- PHASE C: LN+SiLU+post w2 + argmax ----------------
        {
            const float* phTn = epre + (size_t)t * NH * NB;    // NORMAL reads (fresh lines)
            int base = w * 64;
            // pass 1: LN stats
            float s1 = 0.f, s2 = 0.f;
            for (int kt = 0; kt < 64; kt += 16) {
                float hbuf[16];
#pragma unroll
                for (int j = 0; j < 16; ++j)
                    hbuf[j] = phTn[(size_t)(base + kt + j) * NB + lane];
#pragma unroll
                for (int j = 0; j < 16; ++j) { s1 += hbuf[j]; s2 = fmaf(hbuf[j], hbuf[j], s2); }
            }
            sRed[w][0][lane] = s1; sRed[w][1][lane] = s2;
            __syncthreads();
            if (tid < 64) {
                float a = 0.f, q = 0.f;
#pragma unroll
                for (int ww = 0; ww < 16; ++ww) { a += sRed[ww][0][tid]; q += sRed[ww][1][tid]; }
                float mean = a * (1.f / NH);
                float var = q * (1.f / NH) - mean * mean;
                smean[tid] = mean;
                srstd[tid] = 1.f / sqrtf(var + EPS);
            }
            __syncthreads();
            float mean = smean[lane], rstd = srstd[lane];
            float acc4[4] = {0.f, 0.f, 0.f, 0.f};
            for (int kt = 0; kt < 64; kt += 16) {
                float hbuf[16];
#pragma unroll
                for (int j = 0; j < 16; ++j)
                    hbuf[j] = phTn[(size_t)(base + kt + j) * NB + lane];   // L2-hot re-read
#pragma unroll
                for (int j4 = 0; j4 < 16; j4 += 4) {
                    int k = base + kt + j4;
                    float4 gv = *(const float4*)&qg[k];
                    float4 bv = *(const float4*)&qbe[k];
                    float x0 = fmaf((hbuf[j4 + 0] - mean) * rstd, gv.x, bv.x);
                    float x1 = fmaf((hbuf[j4 + 1] - mean) * rstd, gv.y, bv.y);
                    float x2 = fmaf((hbuf[j4 + 2] - mean) * rstd, gv.z, bv.z);
                    float x3 = fmaf((hbuf[j4 + 3] - mean) * rstd, gv.w, bv.w);
                    float sl0 = x0 / (1.f + __expf(-x0));
                    float sl1 = x1 / (1.f + __expf(-x1));
                    float sl2 = x2 / (1.f + __expf(-x2));
                    float sl3 = x3 / (1.f + __expf(-x3));
#pragma unroll
                    for (int jj = 0; jj < 4; ++jj) {
                        float4 wv = *(const float4*)&qw2[(size_t)(d0 + jj) * NH + k];
                        acc4[jj] = fmaf(wv.x, sl0, acc4[jj]);
                        acc4[jj] = fmaf(wv.y, sl1, acc4[jj]);
                        acc4[jj] = fmaf(wv.z, sl2, acc4[jj]);
                        acc4[jj] = fmaf(wv.w, sl3, acc4[jj]);
                    }
                }
            }
#pragma unroll
            for (int jj = 0; jj < 4; ++jj) sRed[w][jj][lane] = acc4[jj];
            __syncthreads();
            if (tid < 256) {
                float s = 0.f;
#pragma unroll
                for (int ww = 0; ww < 16; ++ww) s += sRed[ww][dd][bb];
                float lg = s + qb2[d0 + dd];
                sV[dd][bb] = lg;
                unsigned bits = __float_as_uint(lg);
                unsigned key = (bits & 0x80000000u) ? ~bits : (bits | 0x80000000u);
                int cls = (d0 + dd) & 31;
                pkst[dd][bb] = ((unsigned long long)key << 32) | (unsigned long long)(31 - cls);
            }
            __syncthreads();
            if (tid < 64) {
                int d2 = tid >> 4, bq = (tid & 15) * 4;
                float4 v = { sV[d2][bq], sV[d2][bq + 1], sV[d2][bq + 2], sV[d2][bq + 3] };
                *(float4*)&lhist[((size_t)t * NSC + d0 + d2) * NB + bq] = v;  // normal store
                unsigned long long m = pkst[0][tid];
                if (pkst[1][tid] > m) m = pkst[1][tid];
                if (pkst[2][tid] > m) m = pkst[2][tid];
                if (pkst[3][tid] > m) m = pkst[3][tid];
                __hip_atomic_fetch_max(&gmax[(d0 >> 5) * 64 + tid], m,
                                       __ATOMIC_RELAXED, __HIP_MEMORY_SCOPE_AGENT);
            }
        }
        // -------- S3 --------
        GRID_BARRIER();
    }
    // final timestep's z indices for k4 (gmax final after S3(63))
    if (blk == 0 && tid < 64) {
#pragma unroll 8
        for (int g = 0; g < 32; ++g) {
            unsigned long long pk = gload64(&gmax[g * 64 + tid]);
            zidx[63 * 32 * NB + g * NB + tid] = (int)(31u - ((unsigned int)pk & 31u));
        }
    }
#undef GRID_BARRIER
}

// =================== K3a: prior w1 + LN stats ===================
__global__ __launch_bounds__(256) void k3_p1(const float* __restrict__ w1p,
                                             const float* __restrict__ b1p,
                                             float* __restrict__ ws)
{
    int blk = blockIdx.x;
    int t = blk >> 6, kg = blk & 63, k0 = kg * 16;
    int tid = threadIdx.x, w = tid >> 6, lane = tid & 63;
    const float* hrow = ws + O_HHIST + (size_t)t * ND * NB;
    float acc[16];
#pragma unroll
    for (int i = 0; i < 16; ++i) acc[i] = 0.f;
    int dd0 = w * 256;
    for (int d = dd0; d < dd0 + 256; d += 4) {
        float hv0 = hrow[(size_t)(d + 0) * NB + lane];
        float hv1 = hrow[(size_t)(d + 1) * NB + lane];
        float hv2 = hrow[(size_t)(d + 2) * NB + lane];
        float hv3 = hrow[(size_t)(d + 3) * NB + lane];
#pragma unroll
        for (int kk = 0; kk < 16; ++kk) {
            float4 wv = *(const float4*)&w1p[(size_t)(k0 + kk) * ND + d];
            acc[kk] = fmaf(wv.x, hv0, acc[kk]);
            acc[kk] = fmaf(wv.y, hv1, acc[kk]);
            acc[kk] = fmaf(wv.z, hv2, acc[kk]);
            acc[kk] = fmaf(wv.w, hv3, acc[kk]);
        }
    }
    __shared__ float red[4][16][64];
    __shared__ float vst[16][64];
#pragma unroll
    for (int kk = 0; kk < 16; ++kk) red[w][kk][lane] = acc[kk];
    __syncthreads();
    float* ph1 = ws + O_EPRE + (size_t)t * NH * NB;  // reuse E_pre region
    for (int q = 0; q < 4; ++q) {
        int slot = tid + q * 256;
        int kk = slot >> 6, b = slot & 63;
        float v = red[0][kk][b] + red[1][kk][b] + red[2][kk][b] + red[3][kk][b] + b1p[k0 + kk];
        ph1[(size_t)(k0 + kk) * NB + b] = v;
        vst[kk][b] = v;
    }
    __syncthreads();
    if (tid < 64) {
        float s1 = 0.f, s2 = 0.f;
#pragma unroll
        for (int kk = 0; kk < 16; ++kk) { float v = vst[kk][tid]; s1 += v; s2 = fmaf(v, v, s2); }
        float* pst = ws + O_PSTAT;
        atomicAdd(&pst[(t * NB + tid) * 2 + 0], s1);
        atomicAdd(&pst[(t * NB + tid) * 2 + 1], s2);
    }
}

// =================== K3b: prior LN+SiLU+w2 -> prior_logits ===================
__global__ __launch_bounds__(256) void k3_p2(const float* __restrict__ gp,
                                             const float* __restrict__ bep,
                                             const float* __restrict__ w2p,
                                             const float* __restrict__ b2p,
                                             float* __restrict__ ws,
                                             float* __restrict__ out)
{
    int blk = blockIdx.x;
    int t = blk >> 6, jg = blk & 63, j0 = jg * 16;
    int tid = threadIdx.x, w = tid >> 6, lane = tid & 63;
    const float* ph1 = ws + O_EPRE + (size_t)t * NH * NB;
    const float* pst = ws + O_PSTAT;
    __shared__ float smean[64], srstd[64];
    if (tid < 64) {
        float s1 = pst[(t * NB + tid) * 2], s2 = pst[(t * NB + tid) * 2 + 1];
        float mean = s1 * (1.f / NH);
        float var = s2 * (1.f / NH) - mean * mean;
        smean[tid] = mean;
        srstd[tid] = 1.f / sqrtf(var + EPS);
    }
    __syncthreads();
    float mean = smean[lane], rstd = srstd[lane];
    float acc[16];
#pragma unroll
    for (int i = 0; i < 16; ++i) acc[i] = 0.f;
    int kk0 = w * 256;
    for (int k = kk0; k < kk0 + 256; k += 4) {
        float4 gv = *(const float4*)&gp[k];
        float4 bv = *(const float4*)&bep[k];
        float v0 = ph1[(size_t)(k + 0) * NB + lane];
        float v1 = ph1[(size_t)(k + 1) * NB + lane];
        float v2 = ph1[(size_t)(k + 2) * NB + lane];
        float v3 = ph1[(size_t)(k + 3) * NB + lane];
        float x0 = fmaf((v0 - mean) * rstd, gv.x, bv.x);
        float x1 = fmaf((v1 - mean) * rstd, gv.y, bv.y);
        float x2 = fmaf((v2 - mean) * rstd, gv.z, bv.z);
        float x3 = fmaf((v3 - mean) * rstd, gv.w, bv.w);
        float sl0 = x0 / (1.f + __expf(-x0));
        float sl1 = x1 / (1.f + __expf(-x1));
        float sl2 = x2 / (1.f + __expf(-x2));
        float sl3 = x3 / (1.f + __expf(-x3));
#pragma unroll
        for (int jj = 0; jj < 16; ++jj) {
            float4 wv = *(const float4*)&w2p[(size_t)(j0 + jj) * NH + k];
            acc[jj] = fmaf(wv.x, sl0, acc[jj]);
            acc[jj] = fmaf(wv.y, sl1, acc[jj]);
            acc[jj] = fmaf(wv.z, sl2, acc[jj]);
            acc[jj] = fmaf(wv.w, sl3, acc[jj]);
        }
    }
    __shared__ float red[4][16][64];
#pragma unroll
    for (int jj = 0; jj < 16; ++jj) red[w][jj][lane] = acc[jj];
    __syncthreads();
    float* prior = out + OUT_PRIOR;
    for (int q = 0; q < 4; ++q) {
        int slot = tid + q * 256;
        int b = slot >> 4, jj = slot & 15;
        float v = red[0][jj][b] + red[1][jj][b] + red[2][jj][b] + red[3][jj][b] + b2p[j0 + jj];
        prior[((size_t)b * NT + t) * NSC + j0 + jj] = v;
    }
}

// =================== K4: write-out transposes ===================
__global__ void k4_out(float* __restrict__ ws, float* __restrict__ out)
{
    int blk = blockIdx.x, tid = threadIdx.x;
    int rr = tid >> 6, ln = tid & 63;
    float* latent = out + OUT_LATENT;
    float* hseq = out + OUT_HSEQ;
    float* post = out + OUT_POST;
    if (blk < 1024) {
        int t = blk >> 4, dt = blk & 15, base_d = dt * 64;
        __shared__ float tile[64][65];
        const float* hh = ws + O_HHIST + (size_t)t * ND * NB;
        for (int q = 0; q < 16; ++q) {
            int row = q * 4 + rr;
            tile[row][ln] = hh[(size_t)(base_d + row) * NB + ln];
        }
        __syncthreads();
        for (int q = 0; q < 16; ++q) {
            int b = q * 4 + rr;
            float v = tile[ln][b];
            hseq[((size_t)b * NT + t) * ND + base_d + ln] = v;
            latent[((size_t)b * NT + t) * 2048 + base_d + ln] = v;
        }
    } else if (blk < 2048) {
        int bb = blk - 1024;
        int t = bb >> 4, jt = bb & 15, base_j = jt * 64;
        __shared__ float tile[64][65];
        const float* lh = ws + O_LHIST + (size_t)t * NSC * NB;
        for (int q = 0; q < 16; ++q) {
            int row = q * 4 + rr;
            tile[row][ln] = lh[(size_t)(base_j + row) * NB + ln];
        }
        __syncthreads();
        for (int q = 0; q < 16; ++q) {
            int b = q * 4 + rr;
            post[((size_t)b * NT + t) * NSC + base_j + ln] = tile[ln][b];
        }
    } else {
        int t = blk - 2048;
        const int* zi = (const int*)(ws + O_ZIDX) + t * 32 * NB;
        __shared__ int zl[32];
        for (int b = 0; b < NB; ++b) {
            if (tid < 32) zl[tid] = zi[tid * NB + b];
            __syncthreads();
            for (int q = 0; q < 4; ++q) {
                int j = q * 256 + tid;
                latent[((size_t)b * NT + t) * 2048 + 1024 + j] = (zl[j >> 5] == (j & 31)) ? 1.f : 0.f;
            }
            __syncthreads();
        }
    }
}

extern "C" void kernel_launch(void* const* d_in, const int* in_sizes, int n_in,
                              void* d_out, int out_size, void* d_ws, size_t ws_size,
                              hipStream_t stream)
{
    const float* embeds  = (const float*)d_in[0];
    const float* actions = (const float*)d_in[1];
    const int*   isfirst = (const int*)d_in[2];
    const float* Wih = (const float*)d_in[3];
    const float* Whh = (const float*)d_in[4];
    const float* bih = (const float*)d_in[5];
    const float* bhh = (const float*)d_in[6];
    const float* pw1r = (const float*)d_in[7];
    const float* pb1r = (const float*)d_in[8];
    const float* pgr  = (const float*)d_in[9];
    const float* pber = (const float*)d_in[10];
    const float* pw2r = (const float*)d_in[11];
    const float* pb2r = (const float*)d_in[12];
    const float* qw1 = (const float*)d_in[13];
    const float* qb1 = (const float*)d_in[14];
    const float* qg  = (const float*)d_in[15];
    const float* qbe = (const float*)d_in[16];
    const float* qw2 = (const float*)d_in[17];
    const float* qb2 = (const float*)d_in[18];
    float* out = (float*)d_out;
    float* ws = (float*)d_ws;

    hipLaunchKernelGGL(k0_prep, dim3(1538), dim3(256), 0, stream, embeds, actions, isfirst, ws);
    hipLaunchKernelGGL(k1_epre, dim3(4096), dim3(256), 0, stream, qw1, ws);

    void* args[] = {(void*)&Wih, (void*)&Whh, (void*)&bih, (void*)&bhh,
                    (void*)&qw1, (void*)&qb1, (void*)&qg, (void*)&qbe,
                    (void*)&qw2, (void*)&qb2, (void*)&ws};
    hipLaunchCooperativeKernel((void*)k2_scan, dim3(256), dim3(1024), args, 0, stream);

    hipLaunchKernelGGL(k3_p1, dim3(4096), dim3(256), 0, stream, pw1r, pb1r, ws);
    hipLaunchKernelGGL(k3_p2, dim3(4096), dim3(256), 0, stream, pgr, pber, pw2r, pb2r, ws, out);
    hipLaunchKernelGGL(k4_out, dim3(2112), dim3(256), 0, stream, ws, out);
}

// Round 3
// 5359.521 us; speedup vs baseline: 1.3106x; 1.3106x over previous
//
#include <hip/hip_runtime.h>

#define NB 64      // batch
#define NT 64      // time
#define ND 1024    // DETER
#define NH 1024    // HID
#define NE 1536    // EMBED
#define NA 6       // ACT
#define NSC 1024   // STOCH*CLASSES
#define GIN 1030   // GRU_IN
#define W1STR 2560 // post_w1 row stride (ND+NE)
#define EPS 1e-5f

typedef float f4v __attribute__((ext_vector_type(4)));

// ---- workspace layout (float offsets) ----
#define O_EPRE   0u            // [T][NH][NB]  epre, then phT[t] in-place, then k3 ph1
#define O_HHIST  4194304u      // [T][ND][NB]
#define O_LHIST  8388608u      // [T][NSC][NB] (post logits, [t][j][b])
#define O_EMBT   4194304u      // overlay on HHIST+LHIST pre-scan: [T][NE][NB]
#define O_BAR    12582912u     // u32[0]=epoch
#define O_FLAGS  12582976u     // u32[c*16] c<8: split arrive counters (64B apart)
#define O_GMAX   12812288u     // u64[32][NB] packed argmax keys
#define O_ZIDX   12816384u     // int[T][32][NB]
#define O_ACTT   12947456u     // [T][NA][NB]
#define O_KEEPT  12972032u     // [T][NB]
#define O_PSTAT  12976128u     // [T][NB][2] prior LN stats (k3)

// out layout (floats)
#define OUT_LATENT 0u
#define OUT_HSEQ   8388608u
#define OUT_POST   12582912u
#define OUT_PRIOR  16777216u

// ---- coherence-point bypass ops (agent scope, relaxed) ----
__device__ __forceinline__ float gload(const float* p) {
    return __uint_as_float(__hip_atomic_load((const unsigned int*)p,
                __ATOMIC_RELAXED, __HIP_MEMORY_SCOPE_AGENT));
}
__device__ __forceinline__ unsigned long long gload64(const unsigned long long* p) {
    return __hip_atomic_load(p, __ATOMIC_RELAXED, __HIP_MEMORY_SCOPE_AGENT);
}
__device__ __forceinline__ void gstore64(unsigned long long* p, unsigned long long v) {
    __hip_atomic_store(p, v, __ATOMIC_RELAXED, __HIP_MEMORY_SCOPE_AGENT);
}
__device__ __forceinline__ unsigned int gload32(const unsigned int* p) {
    return __hip_atomic_load(p, __ATOMIC_RELAXED, __HIP_MEMORY_SCOPE_AGENT);
}
__device__ __forceinline__ void gstore32(unsigned int* p, unsigned int v) {
    __hip_atomic_store(p, v, __ATOMIC_RELAXED, __HIP_MEMORY_SCOPE_AGENT);
}
// 16B L2-bypass store (device-coherent): lands at L3, visible to all XCDs
// after vmcnt(0)+flag release. Safe only for lines with no valid L2 copies
// anywhere (t-indexed, first touch) — holds for hhist[t]/epre[t] writes.
__device__ __forceinline__ void gstore128(float* p, f4v v) {
    asm volatile("global_store_dwordx4 %0, %1, off sc0 sc1"
                 :: "v"(p), "v"(v) : "memory");
}

// =================== K0: transposes + zero-init ===================
__global__ void k0_prep(const float* __restrict__ embeds,
                        const float* __restrict__ actions,
                        const int* __restrict__ isfirst,
                        float* __restrict__ ws)
{
    int blk = blockIdx.x, tid = threadIdx.x;
    int rr = tid >> 6, ln = tid & 63;
    if (blk < 1536) {
        // embeds (B,T,E) -> emb_T [t][e][b]
        int t = blk / 24, et = blk % 24, e0 = et * 64;
        __shared__ float tile[64][65];
        for (int q = 0; q < 16; ++q) {
            int b = q * 4 + rr;
            tile[b][ln] = embeds[((size_t)b * NT + t) * NE + e0 + ln];
        }
        __syncthreads();
        float* embT = ws + O_EMBT + (size_t)t * NE * NB;
        for (int q = 0; q < 16; ++q) {
            int e = q * 4 + rr;
            embT[(size_t)(e0 + e) * NB + ln] = tile[ln][e];
        }
    } else if (blk == 1536) {
        for (int i = tid; i < NT * NA * NB; i += 256) {
            int t = i / (NA * NB); int rem = i % (NA * NB);
            int a = rem / NB; int b = rem % NB;
            ws[O_ACTT + i] = actions[((size_t)b * NT + t) * NA + a];
        }
        for (int i = tid; i < NT * NB; i += 256) {
            int t = i / NB, b = i % NB;
            ws[O_KEEPT + i] = 1.f - (float)isfirst[(size_t)b * NT + t];
        }
    } else {
        if (tid == 0) *(unsigned int*)(ws + O_BAR) = 0u;
        for (int i = tid; i < 256 * 32; i += 256)
            ((unsigned int*)(ws + O_FLAGS))[i] = 0u;
        for (int i = tid; i < NT * NB * 2; i += 256)
            ws[O_PSTAT + i] = 0.f;
    }
}

// =================== K1: E_pre = emb @ post_w1[:,1024:]^T ===================
__global__ __launch_bounds__(256) void k1_epre(const float* __restrict__ qw1,
                                               float* __restrict__ ws)
{
    int blk = blockIdx.x;
    int t = blk >> 6, kg = blk & 63, k0 = kg * 16;
    int tid = threadIdx.x, w = tid >> 6, lane = tid & 63;
    const float* embT = ws + O_EMBT + (size_t)t * NE * NB;
    float acc[16];
#pragma unroll
    for (int i = 0; i < 16; ++i) acc[i] = 0.f;
    int e0 = w * 384;
    for (int e = e0; e < e0 + 384; e += 4) {
        float ev0 = embT[(size_t)(e + 0) * NB + lane];
        float ev1 = embT[(size_t)(e + 1) * NB + lane];
        float ev2 = embT[(size_t)(e + 2) * NB + lane];
        float ev3 = embT[(size_t)(e + 3) * NB + lane];
#pragma unroll
        for (int kk = 0; kk < 16; ++kk) {
            float4 wv = *(const float4*)&qw1[(size_t)(k0 + kk) * W1STR + ND + e];
            acc[kk] = fmaf(wv.x, ev0, acc[kk]);
            acc[kk] = fmaf(wv.y, ev1, acc[kk]);
            acc[kk] = fmaf(wv.z, ev2, acc[kk]);
            acc[kk] = fmaf(wv.w, ev3, acc[kk]);
        }
    }
    __shared__ float red[4][16][64];
#pragma unroll
    for (int kk = 0; kk < 16; ++kk) red[w][kk][lane] = acc[kk];
    __syncthreads();
    float* epre = ws + O_EPRE + (size_t)t * NH * NB;
    for (int q = 0; q < 4; ++q) {
        int slot = tid + q * 256;
        int kk = slot >> 6, b = slot & 63;
        float v = red[0][kk][b] + red[1][kk][b] + red[2][kk][b] + red[3][kk][b];
        epre[(size_t)(k0 + kk) * NB + b] = v;
    }
}

// =================== K2: the scan ===================
// 256 blocks x 512 threads (8 waves — the L2-resident config from round 0).
// Key change: the Whh·h matmul for step t+1 is FUSED into phase B's stream
// of h[t] (accP registers persist across barriers), so phase A has no
// h-broadcast read at all. Barrier = 8-way split arrive counters.
__global__ __launch_bounds__(512, 2)
void k2_scan(const float* __restrict__ Wih, const float* __restrict__ Whh,
             const float* __restrict__ bih, const float* __restrict__ bhh,
             const float* __restrict__ qw1, const float* __restrict__ qb1,
             const float* __restrict__ qg,  const float* __restrict__ qbe,
             const float* __restrict__ qw2, const float* __restrict__ qb2,
             float* __restrict__ ws)
{
    const int blk = blockIdx.x, tid = threadIdx.x;
    const int w = tid >> 6, lane = tid & 63;       // w in [0,8)
    const int d0 = blk * 4;                        // owned 4 dims
    const int dd = (tid >> 6) & 3, bb = tid & 63;  // finalize mapping (tid<256)

    float* hhist = ws + O_HHIST;
    float* lhist = ws + O_LHIST;
    float* epre  = ws + O_EPRE;          // also phT[t] in-place
    unsigned int* epoch = (unsigned int*)(ws + O_BAR);
    unsigned int* arr   = (unsigned int*)(ws + O_FLAGS);
    unsigned long long* gmax = (unsigned long long*)(ws + O_GMAX);
    int* zidx = (int*)(ws + O_ZIDX);
    const float* actT  = ws + O_ACTT;
    const float* keepT = ws + O_KEEPT;

    __shared__ __align__(16) float sWhh[12][1024];   // 48KB: rows gate*4+dd
    __shared__ float sRed[8][12][64];                 // 24KB
    __shared__ float sV[4][64];                       // 1KB staging for vec stores
    __shared__ float smean[64], srstd[64];
    __shared__ unsigned long long pkst[4][64];        // 2KB
    __shared__ float sGx2[2][3][4][64];               // 6KB split gate partials
    __shared__ unsigned int zcS[8][64];               // 2KB packed z indices

    // ---- stage Whh slice once (coalesced float4 per row) ----
    for (int i4 = tid; i4 < 12 * 256; i4 += 512) {
        int r = i4 >> 8, k4 = (i4 & 255) * 4;
        int row = (r >> 2) * 1024 + d0 + (r & 3);
        *(float4*)&sWhh[r][k4] = *(const float4*)&Whh[(size_t)row * ND + k4];
    }
    __syncthreads();

    unsigned int ep = 0;
    float accP[12];                       // Whh·h partials, persist across barriers
#pragma unroll
    for (int r = 0; r < 12; ++r) accP[r] = 0.f;

#define GRID_BARRIER()  do { \
        ++ep; \
        asm volatile("s_waitcnt vmcnt(0) lgkmcnt(0)" ::: "memory"); \
        __syncthreads(); \
        if (blk == 0) { \
            if (tid == 0) { \
                for (;;) { \
                    unsigned int s = 0; \
                    _Pragma("unroll") \
                    for (int c = 0; c < 8; ++c) s += gload32(&arr[c * 16]); \
                    if (s >= 255u * ep) break; \
                    __builtin_amdgcn_s_sleep(1); \
                } \
                gstore32(epoch, ep); \
            } \
        } else { \
            if (tid == 0) { \
                __hip_atomic_fetch_add(&arr[(blk & 7) * 16], 1u, \
                        __ATOMIC_RELAXED, __HIP_MEMORY_SCOPE_AGENT); \
                while (gload32(epoch) < ep) __builtin_amdgcn_s_sleep(4); \
            } \
        } \
        __syncthreads(); \
    } while (0)

    for (int t = 0; t < NT; ++t) {
        // ---------------- PHASE A: gates -> h_new (no matmul!) ----------------
        {
            // (1) publish persisted Whh partials; distributed gmax unpack
#pragma unroll
            for (int r = 0; r < 12; ++r) sRed[w][r][lane] = accP[r];
            if (t > 0) {
                int j = w, b = lane;        // 8x64 = 512 threads cover 32x64 keys
                unsigned long long pk0 = gload64(&gmax[(4 * j + 0) * 64 + b]);
                unsigned long long pk1 = gload64(&gmax[(4 * j + 1) * 64 + b]);
                unsigned long long pk2 = gload64(&gmax[(4 * j + 2) * 64 + b]);
                unsigned long long pk3 = gload64(&gmax[(4 * j + 3) * 64 + b]);
                unsigned int c0 = 31u - ((unsigned int)pk0 & 31u);
                unsigned int c1 = 31u - ((unsigned int)pk1 & 31u);
                unsigned int c2 = 31u - ((unsigned int)pk2 & 31u);
                unsigned int c3 = 31u - ((unsigned int)pk3 & 31u);
                zcS[j][b] = c0 | (c1 << 8) | (c2 << 16) | (c3 << 24);
                if (blk == 0) {
                    int* zr = zidx + (t - 1) * 32 * NB;
                    zr[(4 * j + 0) * NB + b] = (int)c0;
                    zr[(4 * j + 1) * NB + b] = (int)c1;
                    zr[(4 * j + 2) * NB + b] = (int)c2;
                    zr[(4 * j + 3) * NB + b] = (int)c3;
                }
            }
            __syncthreads();
            // (2) split z/act gather: half = tid>>8 handles 16 groups x 3 gates
            {
                int half = tid >> 8, dd3 = (tid >> 6) & 3, bb3 = tid & 63;
                int d = d0 + dd3;
                float keep = keepT[t * NB + bb3];
#pragma unroll
                for (int g3 = 0; g3 < 3; ++g3) {
                    const float* Wrow = Wih + (size_t)(g3 * 1024 + d) * GIN;
                    float part = 0.f;
                    if (t > 0) {
                        float s = 0.f;
                        int gbase = half * 16;
#pragma unroll
                        for (int g = 0; g < 16; ++g) {
                            int gg = gbase + g;
                            int c = (int)((zcS[gg >> 2][bb3] >> ((gg & 3) * 8)) & 31u);
                            s += Wrow[gg * 32 + c];
                        }
                        part = keep * s;
                    }
                    if (half == 0) {
                        part += bih[g3 * 1024 + d];
#pragma unroll
                        for (int a = 0; a < NA; ++a)
                            part = fmaf(Wrow[ND + a], actT[(t * NA + a) * NB + bb3], part);
                    }
                    sGx2[half][g3][dd3][bb3] = part;
                }
            }
            __syncthreads();
            // (3) finalize gates + h_new
            if (tid < 256) {
                int d = d0 + dd;
                float keep = keepT[t * NB + bb];
                float gh0 = 0.f, gh1 = 0.f, gh2 = 0.f;
#pragma unroll
                for (int ww = 0; ww < 8; ++ww) {
                    gh0 += sRed[ww][dd + 0][bb];
                    gh1 += sRed[ww][dd + 4][bb];
                    gh2 += sRed[ww][dd + 8][bb];
                }
                float ghr = fmaf(keep, gh0, bhh[d]);
                float ghz = fmaf(keep, gh1, bhh[1024 + d]);
                float ghn = fmaf(keep, gh2, bhh[2048 + d]);
                float gxr = sGx2[0][0][dd][bb] + sGx2[1][0][dd][bb];
                float gxz = sGx2[0][1][dd][bb] + sGx2[1][1][dd][bb];
                float gxn = sGx2[0][2][dd][bb] + sGx2[1][2][dd][bb];
                float r = 1.f / (1.f + __expf(-(gxr + ghr)));
                float u = 1.f / (1.f + __expf(-(gxz + ghz)));
                float n = tanhf(gxn + r * ghn);
                float hprevm = 0.f;
                if (t > 0)
                    hprevm = keep * hhist[((size_t)(t - 1) * ND + d) * NB + bb];  // L2-warm
                sV[dd][bb] = (1.f - u) * n + u * hprevm;
            }
            __syncthreads();
            if (tid < 64) {   // vectorized bypass store: 4 rows x 16 float4
                int d2 = tid >> 4, bq = (tid & 15) * 4;
                f4v v = { sV[d2][bq], sV[d2][bq + 1], sV[d2][bq + 2], sV[d2][bq + 3] };
                gstore128(&hhist[((size_t)t * ND + d0 + d2) * NB + bq], v);
            }
        }
        // -------- S1 --------
        GRID_BARRIER();
        // -------- PHASE B: fused qw1·h[t] (for phT) + Whh·h[t] (for t+1) --------
        {
            const float* hrow = hhist + (size_t)t * ND * NB;   // normal (first touch fresh)
            float eprev = 0.f;
            if (tid < 256)   // issue bypass read early (hidden under FMA loop)
                eprev = gload(&epre[((size_t)t * NH + d0 + dd) * NB + bb]);
            float acc4[4] = {0.f, 0.f, 0.f, 0.f};
#pragma unroll
            for (int r = 0; r < 12; ++r) accP[r] = 0.f;
            int base = w * 128;
            for (int kt = 0; kt < 128; kt += 16) {
                float hbuf[16];
#pragma unroll
                for (int j = 0; j < 16; ++j)
                    hbuf[j] = hrow[(size_t)(base + kt + j) * NB + lane];
#pragma unroll
                for (int j4 = 0; j4 < 16; j4 += 4) {
                    int k = base + kt + j4;
#pragma unroll
                    for (int r = 0; r < 12; ++r) {
                        float4 wv = *(const float4*)&sWhh[r][k];   // LDS broadcast
                        accP[r] = fmaf(wv.x, hbuf[j4 + 0], accP[r]);
                        accP[r] = fmaf(wv.y, hbuf[j4 + 1], accP[r]);
                        accP[r] = fmaf(wv.z, hbuf[j4 + 2], accP[r]);
                        accP[r] = fmaf(wv.w, hbuf[j4 + 3], accP[r]);
                    }
#pragma unroll
                    for (int rr = 0; rr < 4; ++rr) {
                        float4 wv = *(const float4*)&qw1[(size_t)(d0 + rr) * W1STR + k];
                        acc4[rr] = fmaf(wv.x, hbuf[j4 + 0], acc4[rr]);
                        acc4[rr] = fmaf(wv.y, hbuf[j4 + 1], acc4[rr]);
                        acc4[rr] = fmaf(wv.z, hbuf[j4 + 2], acc4[rr]);
                        acc4[rr] = fmaf(wv.w, hbuf[j4 + 3], acc4[rr]);
                    }
                }
            }
#pragma unroll
            for (int rr = 0; rr < 4; ++rr) sRed[w][rr][lane] = acc4[rr];
            if (blk == 0 && tid >= 256) {   // reset argmax accumulators (waves 4-7)
                for (int i = tid - 256; i < 2048; i += 256) gstore64(&gmax[i], 0ull);
            }
            __syncthreads();
            if (tid < 256) {
                float s = 0.f;
#pragma unroll
                for (int ww = 0; ww < 8; ++ww) s += sRed[ww][dd][bb];
                sV[dd][bb] = s + qb1[d0 + dd] + eprev;
            }
            __syncthreads();
            if (tid < 64) {
                int d2 = tid >> 4, bq = (tid & 15) * 4;
                f4v v = { sV[d2][bq], sV[d2][bq + 1], sV[d2][bq + 2], sV[d2][bq + 3] };
                gstore128(&epre[((size_t)t * NH + d0 + d2) * NB + bq], v);
            }
        }
        // -------- S2 --------
        GRID_BARRIER();
        // ---------------- PHASE C: LN+SiLU+post w2 + argmax ----------------
        {
            const float* phTn = epre + (size_t)t * NH * NB;    // NORMAL reads (fresh lines)
            int base = w * 128;
            // pass 1: LN stats
            float s1 = 0.f, s2 = 0.f;
            for (int kt = 0; kt < 128; kt += 16) {
                float hbuf[16];
#pragma unroll
                for (int j = 0; j < 16; ++j)
                    hbuf[j] = phTn[(size_t)(base + kt + j) * NB + lane];
#pragma unroll
                for (int j = 0; j < 16; ++j) { s1 += hbuf[j]; s2 = fmaf(hbuf[j], hbuf[j], s2); }
            }
            sRed[w][0][lane] = s1; sRed[w][1][lane] = s2;
            __syncthreads();
            if (tid < 64) {
                float a = 0.f, q = 0.f;
#pragma unroll
                for (int ww = 0; ww < 8; ++ww) { a += sRed[ww][0][tid]; q += sRed[ww][1][tid]; }
                float mean = a * (1.f / NH);
                float var = q * (1.f / NH) - mean * mean;
                smean[tid] = mean;
                srstd[tid] = 1.f / sqrtf(var + EPS);
            }
            __syncthreads();
            float mean = smean[lane], rstd = srstd[lane];
            float acc4[4] = {0.f, 0.f, 0.f, 0.f};
            for (int kt = 0; kt < 128; kt += 16) {
                float hbuf[16];
#pragma unroll
                for (int j = 0; j < 16; ++j)
                    hbuf[j] = phTn[(size_t)(base + kt + j) * NB + lane];   // L2-hot re-read
#pragma unroll
                for (int j4 = 0; j4 < 16; j4 += 4) {
                    int k = base + kt + j4;
                    float4 gv = *(const float4*)&qg[k];
                    float4 bv = *(const float4*)&qbe[k];
                    float x0 = fmaf((hbuf[j4 + 0] - mean) * rstd, gv.x, bv.x);
                    float x1 = fmaf((hbuf[j4 + 1] - mean) * rstd, gv.y, bv.y);
                    float x2 = fmaf((hbuf[j4 + 2] - mean) * rstd, gv.z, bv.z);
                    float x3 = fmaf((hbuf[j4 + 3] - mean) * rstd, gv.w, bv.w);
                    float sl0 = x0 / (1.f + __expf(-x0));
                    float sl1 = x1 / (1.f + __expf(-x1));
                    float sl2 = x2 / (1.f + __expf(-x2));
                    float sl3 = x3 / (1.f + __expf(-x3));
#pragma unroll
                    for (int jj = 0; jj < 4; ++jj) {
                        float4 wv = *(const float4*)&qw2[(size_t)(d0 + jj) * NH + k];
                        acc4[jj] = fmaf(wv.x, sl0, acc4[jj]);
                        acc4[jj] = fmaf(wv.y, sl1, acc4[jj]);
                        acc4[jj] = fmaf(wv.z, sl2, acc4[jj]);
                        acc4[jj] = fmaf(wv.w, sl3, acc4[jj]);
                    }
                }
            }
#pragma unroll
            for (int jj = 0; jj < 4; ++jj) sRed[w][jj][lane] = acc4[jj];
            __syncthreads();
            if (tid < 256) {
                float s = 0.f;
#pragma unroll
                for (int ww = 0; ww < 8; ++ww) s += sRed[ww][dd][bb];
                float lg = s + qb2[d0 + dd];
                sV[dd][bb] = lg;
                unsigned bits = __float_as_uint(lg);
                unsigned key = (bits & 0x80000000u) ? ~bits : (bits | 0x80000000u);
                int cls = (d0 + dd) & 31;
                pkst[dd][bb] = ((unsigned long long)key << 32) | (unsigned long long)(31 - cls);
            }
            __syncthreads();
            if (tid < 64) {
                int d2 = tid >> 4, bq = (tid & 15) * 4;
                float4 v = { sV[d2][bq], sV[d2][bq + 1], sV[d2][bq + 2], sV[d2][bq + 3] };
                *(float4*)&lhist[((size_t)t * NSC + d0 + d2) * NB + bq] = v;  // normal store
                unsigned long long m = pkst[0][tid];
                if (pkst[1][tid] > m) m = pkst[1][tid];
                if (pkst[2][tid] > m) m = pkst[2][tid];
                if (pkst[3][tid] > m) m = pkst[3][tid];
                __hip_atomic_fetch_max(&gmax[(d0 >> 5) * 64 + tid], m,
                                       __ATOMIC_RELAXED, __HIP_MEMORY_SCOPE_AGENT);
            }
        }
        // -------- S3 --------
        GRID_BARRIER();
    }
    // final timestep's z indices for k4 (gmax final after S3(63))
    if (blk == 0) {
        int j = w, b = lane;
#pragma unroll
        for (int i = 0; i < 4; ++i) {
            unsigned long long pk = gload64(&gmax[(4 * j + i) * 64 + b]);
            zidx[63 * 32 * NB + (4 * j + i) * NB + b] = (int)(31u - ((unsigned int)pk & 31u));
        }
    }
#undef GRID_BARRIER
}

// =================== K3a: prior w1 + LN stats ===================
__global__ __launch_bounds__(256) void k3_p1(const float* __restrict__ w1p,
                                             const float* __restrict__ b1p,
                                             float* __restrict__ ws)
{
    int blk = blockIdx.x;
    int t = blk >> 6, kg = blk & 63, k0 = kg * 16;
    int tid = threadIdx.x, w = tid >> 6, lane = tid & 63;
    const float* hrow = ws + O_HHIST + (size_t)t * ND * NB;
    float acc[16];
#pragma unroll
    for (int i = 0; i < 16; ++i) acc[i] = 0.f;
    int dd0 = w * 256;
    for (int d = dd0; d < dd0 + 256; d += 4) {
        float hv0 = hrow[(size_t)(d + 0) * NB + lane];
        float hv1 = hrow[(size_t)(d + 1) * NB + lane];
        float hv2 = hrow[(size_t)(d + 2) * NB + lane];
        float hv3 = hrow[(size_t)(d + 3) * NB + lane];
#pragma unroll
        for (int kk = 0; kk < 16; ++kk) {
            float4 wv = *(const float4*)&w1p[(size_t)(k0 + kk) * ND + d];
            acc[kk] = fmaf(wv.x, hv0, acc[kk]);
            acc[kk] = fmaf(wv.y, hv1, acc[kk]);
            acc[kk] = fmaf(wv.z, hv2, acc[kk]);
            acc[kk] = fmaf(wv.w, hv3, acc[kk]);
        }
    }
    __shared__ float red[4][16][64];
    __shared__ float vst[16][64];
#pragma unroll
    for (int kk = 0; kk < 16; ++kk) red[w][kk][lane] = acc[kk];
    __syncthreads();
    float* ph1 = ws + O_EPRE + (size_t)t * NH * NB;  // reuse E_pre region
    for (int q = 0; q < 4; ++q) {
        int slot = tid + q * 256;
        int kk = slot >> 6, b = slot & 63;
        float v = red[0][kk][b] + red[1][kk][b] + red[2][kk][b] + red[3][kk][b] + b1p[k0 + kk];
        ph1[(size_t)(k0 + kk) * NB + b] = v;
        vst[kk][b] = v;
    }
    __syncthreads();
    if (tid < 64) {
        float s1 = 0.f, s2 = 0.f;
#pragma unroll
        for (int kk = 0; kk < 16; ++kk) { float v = vst[kk][tid]; s1 += v; s2 = fmaf(v, v, s2); }
        float* pst = ws + O_PSTAT;
        atomicAdd(&pst[(t * NB + tid) * 2 + 0], s1);
        atomicAdd(&pst[(t * NB + tid) * 2 + 1], s2);
    }
}

// =================== K3b: prior LN+SiLU+w2 -> prior_logits ===================
__global__ __launch_bounds__(256) void k3_p2(const float* __restrict__ gp,
                                             const float* __restrict__ bep,
                                             const float* __restrict__ w2p,
                                             const float* __restrict__ b2p,
                                             float* __restrict__ ws,
                                             float* __restrict__ out)
{
    int blk = blockIdx.x;
    int t = blk >> 6, jg = blk & 63, j0 = jg * 16;
    int tid = threadIdx.x, w = tid >> 6, lane = tid & 63;
    const float* ph1 = ws + O_EPRE + (size_t)t * NH * NB;
    const float* pst = ws + O_PSTAT;
    __shared__ float smean[64], srstd[64];
    if (tid < 64) {
        float s1 = pst[(t * NB + tid) * 2], s2 = pst[(t * NB + tid) * 2 + 1];
        float mean = s1 * (1.f / NH);
        float var = s2 * (1.f / NH) - mean * mean;
        smean[tid] = mean;
        srstd[tid] = 1.f / sqrtf(var + EPS);
    }
    __syncthreads();
    float mean = smean[lane], rstd = srstd[lane];
    float acc[16];
#pragma unroll
    for (int i = 0; i < 16; ++i) acc[i] = 0.f;
    int kk0 = w * 256;
    for (int k = kk0; k < kk0 + 256; k += 4) {
        float4 gv = *(const float4*)&gp[k];
        float4 bv = *(const float4*)&bep[k];
        float v0 = ph1[(size_t)(k + 0) * NB + lane];
        float v1 = ph1[(size_t)(k + 1) * NB + lane];
        float v2 = ph1[(size_t)(k + 2) * NB + lane];
        float v3 = ph1[(size_t)(k + 3) * NB + lane];
        float x0 = fmaf((v0 - mean) * rstd, gv.x, bv.x);
        float x1 = fmaf((v1 - mean) * rstd, gv.y, bv.y);
        float x2 = fmaf((v2 - mean) * rstd, gv.z, bv.z);
        float x3 = fmaf((v3 - mean) * rstd, gv.w, bv.w);
        float sl0 = x0 / (1.f + __expf(-x0));
        float sl1 = x1 / (1.f + __expf(-x1));
        float sl2 = x2 / (1.f + __expf(-x2));
        float sl3 = x3 / (1.f + __expf(-x3));
#pragma unroll
        for (int jj = 0; jj < 16; ++jj) {
            float4 wv = *(const float4*)&w2p[(size_t)(j0 + jj) * NH + k];
            acc[jj] = fmaf(wv.x, sl0, acc[jj]);
            acc[jj] = fmaf(wv.y, sl1, acc[jj]);
            acc[jj] = fmaf(wv.z, sl2, acc[jj]);
            acc[jj] = fmaf(wv.w, sl3, acc[jj]);
        }
    }
    __shared__ float red[4][16][64];
#pragma unroll
    for (int jj = 0; jj < 16; ++jj) red[w][jj][lane] = acc[jj];
    __syncthreads();
    float* prior = out + OUT_PRIOR;
    for (int q = 0; q < 4; ++q) {
        int slot = tid + q * 256;
        int b = slot >> 4, jj = slot & 15;
        float v = red[0][jj][b] + red[1][jj][b] + red[2][jj][b] + red[3][jj][b] + b2p[j0 + jj];
        prior[((size_t)b * NT + t) * NSC + j0 + jj] = v;
    }
}

// =================== K4: write-out transposes ===================
__global__ void k4_out(float* __restrict__ ws, float* __restrict__ out)
{
    int blk = blockIdx.x, tid = threadIdx.x;
    int rr = tid >> 6, ln = tid & 63;
    float* latent = out + OUT_LATENT;
    float* hseq = out + OUT_HSEQ;
    float* post = out + OUT_POST;
    if (blk < 1024) {
        int t = blk >> 4, dt = blk & 15, base_d = dt * 64;
        __shared__ float tile[64][65];
        const float* hh = ws + O_HHIST + (size_t)t * ND * NB;
        for (int q = 0; q < 16; ++q) {
            int row = q * 4 + rr;
            tile[row][ln] = hh[(size_t)(base_d + row) * NB + ln];
        }
        __syncthreads();
        for (int q = 0; q < 16; ++q) {
            int b = q * 4 + rr;
            float v = tile[ln][b];
            hseq[((size_t)b * NT + t) * ND + base_d + ln] = v;
            latent[((size_t)b * NT + t) * 2048 + base_d + ln] = v;
        }
    } else if (blk < 2048) {
        int bb = blk - 1024;
        int t = bb >> 4, jt = bb & 15, base_j = jt * 64;
        __shared__ float tile[64][65];
        const float* lh = ws + O_LHIST + (size_t)t * NSC * NB;
        for (int q = 0; q < 16; ++q) {
            int row = q * 4 + rr;
            tile[row][ln] = lh[(size_t)(base_j + row) * NB + ln];
        }
        __syncthreads();
        for (int q = 0; q < 16; ++q) {
            int b = q * 4 + rr;
            post[((size_t)b * NT + t) * NSC + base_j + ln] = tile[ln][b];
        }
    } else {
        int t = blk - 2048;
        const int* zi = (const int*)(ws + O_ZIDX) + t * 32 * NB;
        __shared__ int zl[32];
        for (int b = 0; b < NB; ++b) {
            if (tid < 32) zl[tid] = zi[tid * NB + b];
            __syncthreads();
            for (int q = 0; q < 4; ++q) {
                int j = q * 256 + tid;
                latent[((size_t)b * NT + t) * 2048 + 1024 + j] = (zl[j >> 5] == (j & 31)) ? 1.f : 0.f;
            }
            __syncthreads();
        }
    }
}

extern "C" void kernel_launch(void* const* d_in, const int* in_sizes, int n_in,
                              void* d_out, int out_size, void* d_ws, size_t ws_size,
                              hipStream_t stream)
{
    const float* embeds  = (const float*)d_in[0];
    const float* actions = (const float*)d_in[1];
    const int*   isfirst = (const int*)d_in[2];
    const float* Wih = (const float*)d_in[3];
    const float* Whh = (const float*)d_in[4];
    const float* bih = (const float*)d_in[5];
    const float* bhh = (const float*)d_in[6];
    const float* pw1r = (const float*)d_in[7];
    const float* pb1r = (const float*)d_in[8];
    const float* pgr  = (const float*)d_in[9];
    const float* pber = (const float*)d_in[10];
    const float* pw2r = (const float*)d_in[11];
    const float* pb2r = (const float*)d_in[12];
    const float* qw1 = (const float*)d_in[13];
    const float* qb1 = (const float*)d_in[14];
    const float* qg  = (const float*)d_in[15];
    const float* qbe = (const float*)d_in[16];
    const float* qw2 = (const float*)d_in[17];
    const float* qb2 = (const float*)d_in[18];
    float* out = (float*)d_out;
    float* ws = (float*)d_ws;

    hipLaunchKernelGGL(k0_prep, dim3(1538), dim3(256), 0, stream, embeds, actions, isfirst, ws);
    hipLaunchKernelGGL(k1_epre, dim3(4096), dim3(256), 0, stream, qw1, ws);

    void* args[] = {(void*)&Wih, (void*)&Whh, (void*)&bih, (void*)&bhh,
                    (void*)&qw1, (void*)&qb1, (void*)&qg, (void*)&qbe,
                    (void*)&qw2, (void*)&qb2, (void*)&ws};
    hipLaunchCooperativeKernel((void*)k2_scan, dim3(256), dim3(512), args, 0, stream);

    hipLaunchKernelGGL(k3_p1, dim3(4096), dim3(256), 0, stream, pw1r, pb1r, ws);
    hipLaunchKernelGGL(k3_p2, dim3(4096), dim3(256), 0, stream, pgr, pber, pw2r, pb2r, ws, out);
    hipLaunchKernelGGL(k4_out, dim3(2112), dim3(256), 0, stream, ws, out);
}

// Round 5
// 5091.373 us; speedup vs baseline: 1.3796x; 1.0527x over previous
//
#include <hip/hip_runtime.h>

#define NB 64      // batch
#define NT 64      // time
#define ND 1024    // DETER
#define NH 1024    // HID
#define NE 1536    // EMBED
#define NA 6       // ACT
#define NSC 1024   // STOCH*CLASSES
#define GIN 1030   // GRU_IN
#define W1STR 2560 // post_w1 row stride (ND+NE)
#define EPS 1e-5f

typedef float f4v __attribute__((ext_vector_type(4)));

// ---- workspace layout (float offsets) ----
#define O_EPRE   0u            // [T][NH][NB]  epre, then phT[t] in-place, then k3 ph1
#define O_HHIST  4194304u      // [T][ND][NB]
#define O_LHIST  8388608u      // [T][NSC][NB] (post logits, [t][j][b])
#define O_EMBT   4194304u      // overlay on HHIST+LHIST pre-scan: [T][NE][NB]
#define O_BAR    12582912u     // u32[0]=epoch
#define O_FLAGS  12582976u     // u32[c*16] c<8: split arrive counters (64B apart)
#define O_GMAX   12812288u     // u64[32][NB] packed argmax keys
#define O_ZIDX   12816384u     // int[T][32][NB]
#define O_ACTT   12947456u     // [T][NA][NB]
#define O_KEEPT  12972032u     // [T][NB]
#define O_PSTAT  12976128u     // [T][NB][2] prior LN stats (k3)

// out layout (floats)
#define OUT_LATENT 0u
#define OUT_HSEQ   8388608u
#define OUT_POST   12582912u
#define OUT_PRIOR  16777216u

// ---- coherence-point bypass ops (agent scope, relaxed) ----
__device__ __forceinline__ float gload(const float* p) {
    return __uint_as_float(__hip_atomic_load((const unsigned int*)p,
                __ATOMIC_RELAXED, __HIP_MEMORY_SCOPE_AGENT));
}
__device__ __forceinline__ unsigned long long gload64(const unsigned long long* p) {
    return __hip_atomic_load(p, __ATOMIC_RELAXED, __HIP_MEMORY_SCOPE_AGENT);
}
__device__ __forceinline__ void gstore64(unsigned long long* p, unsigned long long v) {
    __hip_atomic_store(p, v, __ATOMIC_RELAXED, __HIP_MEMORY_SCOPE_AGENT);
}
__device__ __forceinline__ unsigned int gload32(const unsigned int* p) {
    return __hip_atomic_load(p, __ATOMIC_RELAXED, __HIP_MEMORY_SCOPE_AGENT);
}
__device__ __forceinline__ void gstore32(unsigned int* p, unsigned int v) {
    __hip_atomic_store(p, v, __ATOMIC_RELAXED, __HIP_MEMORY_SCOPE_AGENT);
}
// 16B L2-bypass store (device-coherent): lands at L3, visible to all XCDs
// after vmcnt(0)+flag release. Safe only for lines with no valid L2 copies
// anywhere (t-indexed, first touch) — holds for hhist[t]/epre[t] writes.
__device__ __forceinline__ void gstore128(float* p, f4v v) {
    asm volatile("global_store_dwordx4 %0, %1, off sc0 sc1"
                 :: "v"(p), "v"(v) : "memory");
}

// =================== K0: transposes + zero-init ===================
__global__ void k0_prep(const float* __restrict__ embeds,
                        const float* __restrict__ actions,
                        const int* __restrict__ isfirst,
                        float* __restrict__ ws)
{
    int blk = blockIdx.x, tid = threadIdx.x;
    int rr = tid >> 6, ln = tid & 63;
    if (blk < 1536) {
        // embeds (B,T,E) -> emb_T [t][e][b]
        int t = blk / 24, et = blk % 24, e0 = et * 64;
        __shared__ float tile[64][65];
        for (int q = 0; q < 16; ++q) {
            int b = q * 4 + rr;
            tile[b][ln] = embeds[((size_t)b * NT + t) * NE + e0 + ln];
        }
        __syncthreads();
        float* embT = ws + O_EMBT + (size_t)t * NE * NB;
        for (int q = 0; q < 16; ++q) {
            int e = q * 4 + rr;
            embT[(size_t)(e0 + e) * NB + ln] = tile[ln][e];
        }
    } else if (blk == 1536) {
        for (int i = tid; i < NT * NA * NB; i += 256) {
            int t = i / (NA * NB); int rem = i % (NA * NB);
            int a = rem / NB; int b = rem % NB;
            ws[O_ACTT + i] = actions[((size_t)b * NT + t) * NA + a];
        }
        for (int i = tid; i < NT * NB; i += 256) {
            int t = i / NB, b = i % NB;
            ws[O_KEEPT + i] = 1.f - (float)isfirst[(size_t)b * NT + t];
        }
    } else {
        if (tid == 0) *(unsigned int*)(ws + O_BAR) = 0u;
        for (int i = tid; i < 256 * 32; i += 256)
            ((unsigned int*)(ws + O_FLAGS))[i] = 0u;
        for (int i = tid; i < NT * NB * 2; i += 256)
            ws[O_PSTAT + i] = 0.f;
    }
}

// =================== K1: E_pre = emb @ post_w1[:,1024:]^T ===================
__global__ __launch_bounds__(256) void k1_epre(const float* __restrict__ qw1,
                                               float* __restrict__ ws)
{
    int blk = blockIdx.x;
    int t = blk >> 6, kg = blk & 63, k0 = kg * 16;
    int tid = threadIdx.x, w = tid >> 6, lane = tid & 63;
    const float* embT = ws + O_EMBT + (size_t)t * NE * NB;
    float acc[16];
#pragma unroll
    for (int i = 0; i < 16; ++i) acc[i] = 0.f;
    int e0 = w * 384;
    for (int e = e0; e < e0 + 384; e += 4) {
        float ev0 = embT[(size_t)(e + 0) * NB + lane];
        float ev1 = embT[(size_t)(e + 1) * NB + lane];
        float ev2 = embT[(size_t)(e + 2) * NB + lane];
        float ev3 = embT[(size_t)(e + 3) * NB + lane];
#pragma unroll
        for (int kk = 0; kk < 16; ++kk) {
            float4 wv = *(const float4*)&qw1[(size_t)(k0 + kk) * W1STR + ND + e];
            acc[kk] = fmaf(wv.x, ev0, acc[kk]);
            acc[kk] = fmaf(wv.y, ev1, acc[kk]);
            acc[kk] = fmaf(wv.z, ev2, acc[kk]);
            acc[kk] = fmaf(wv.w, ev3, acc[kk]);
        }
    }
    __shared__ float red[4][16][64];
#pragma unroll
    for (int kk = 0; kk < 16; ++kk) red[w][kk][lane] = acc[kk];
    __syncthreads();
    float* epre = ws + O_EPRE + (size_t)t * NH * NB;
    for (int q = 0; q < 4; ++q) {
        int slot = tid + q * 256;
        int kk = slot >> 6, b = slot & 63;
        float v = red[0][kk][b] + red[1][kk][b] + red[2][kk][b] + red[3][kk][b];
        epre[(size_t)(k0 + kk) * NB + b] = v;
    }
}

// =================== K2: the scan ===================
// 256 blocks x 512 threads (proven round-3 geometry). NEW: all per-block
// weight rows (qw1, qw2, qg, qbe) staged in LDS once before the t-loop —
// removes the ~3.6MB/t per-XCD weight re-fetch from L3 that sat on the
// 2-wave/SIMD critical path. Fused B-phase computes qw1·h (now) + Whh·h
// (for t+1, persisted in accP registers). Barrier = 8-way split counters.
__global__ __launch_bounds__(512, 2)
void k2_scan(const float* __restrict__ Wih, const float* __restrict__ Whh,
             const float* __restrict__ bih, const float* __restrict__ bhh,
             const float* __restrict__ qw1, const float* __restrict__ qb1,
             const float* __restrict__ qg,  const float* __restrict__ qbe,
             const float* __restrict__ qw2, const float* __restrict__ qb2,
             float* __restrict__ ws)
{
    const int blk = blockIdx.x, tid = threadIdx.x;
    const int w = tid >> 6, lane = tid & 63;       // w in [0,8)
    const int d0 = blk * 4;                        // owned 4 dims
    const int dd = (tid >> 6) & 3, bb = tid & 63;  // finalize mapping (tid<256)

    float* hhist = ws + O_HHIST;
    float* lhist = ws + O_LHIST;
    float* epre  = ws + O_EPRE;          // also phT[t] in-place
    unsigned int* epoch = (unsigned int*)(ws + O_BAR);
    unsigned int* arr   = (unsigned int*)(ws + O_FLAGS);
    unsigned long long* gmax = (unsigned long long*)(ws + O_GMAX);
    int* zidx = (int*)(ws + O_ZIDX);
    const float* actT  = ws + O_ACTT;
    const float* keepT = ws + O_KEEPT;

    __shared__ __align__(16) float sWhh[12][1024];   // 48KB: rows gate*4+dd
    __shared__ __align__(16) float sQw1[4][1024];    // 16KB
    __shared__ __align__(16) float sQw2[4][1024];    // 16KB
    __shared__ __align__(16) float sQg[1024];        // 4KB
    __shared__ __align__(16) float sQbe[1024];       // 4KB
    __shared__ float sRed[8][12][64];                 // 24KB
    __shared__ float sV[4][64];                       // 1KB staging for vec stores
    __shared__ float smean[64], srstd[64];
    __shared__ unsigned long long pkst[4][64];        // 2KB
    __shared__ float sGx2[2][3][4][64];               // 6KB split gate partials
    __shared__ unsigned int zcS[8][64];               // 2KB packed z indices

    // ---- stage Whh slice + per-block weight rows once (coalesced float4) ----
    for (int i4 = tid; i4 < 12 * 256; i4 += 512) {
        int r = i4 >> 8, k4 = (i4 & 255) * 4;
        int row = (r >> 2) * 1024 + d0 + (r & 3);
        *(float4*)&sWhh[r][k4] = *(const float4*)&Whh[(size_t)row * ND + k4];
    }
    for (int i4 = tid; i4 < 4 * 256; i4 += 512) {
        int r = i4 >> 8, k4 = (i4 & 255) * 4;
        *(float4*)&sQw1[r][k4] = *(const float4*)&qw1[(size_t)(d0 + r) * W1STR + k4];
        *(float4*)&sQw2[r][k4] = *(const float4*)&qw2[(size_t)(d0 + r) * NH + k4];
    }
    if (tid < 256) {
        int k4 = tid * 4;
        *(float4*)&sQg[k4]  = *(const float4*)&qg[k4];
        *(float4*)&sQbe[k4] = *(const float4*)&qbe[k4];
    }
    __syncthreads();

    unsigned int ep = 0;
    float accP[12];                       // Whh·h partials, persist across barriers
#pragma unroll
    for (int r = 0; r < 12; ++r) accP[r] = 0.f;

#define GRID_BARRIER()  do { \
        ++ep; \
        asm volatile("s_waitcnt vmcnt(0) lgkmcnt(0)" ::: "memory"); \
        __syncthreads(); \
        if (blk == 0) { \
            if (tid == 0) { \
                for (;;) { \
                    unsigned int s = 0; \
                    _Pragma("unroll") \
                    for (int c = 0; c < 8; ++c) s += gload32(&arr[c * 16]); \
                    if (s >= 255u * ep) break; \
                    __builtin_amdgcn_s_sleep(1); \
                } \
                gstore32(epoch, ep); \
            } \
        } else { \
            if (tid == 0) { \
                __hip_atomic_fetch_add(&arr[(blk & 7) * 16], 1u, \
                        __ATOMIC_RELAXED, __HIP_MEMORY_SCOPE_AGENT); \
                while (gload32(epoch) < ep) __builtin_amdgcn_s_sleep(4); \
            } \
        } \
        __syncthreads(); \
    } while (0)

    for (int t = 0; t < NT; ++t) {
        // ---------------- PHASE A: gates -> h_new (no matmul!) ----------------
        {
            // (1) publish persisted Whh partials; distributed gmax unpack
#pragma unroll
            for (int r = 0; r < 12; ++r) sRed[w][r][lane] = accP[r];
            if (t > 0) {
                int j = w, b = lane;        // 8x64 = 512 threads cover 32x64 keys
                unsigned long long pk0 = gload64(&gmax[(4 * j + 0) * 64 + b]);
                unsigned long long pk1 = gload64(&gmax[(4 * j + 1) * 64 + b]);
                unsigned long long pk2 = gload64(&gmax[(4 * j + 2) * 64 + b]);
                unsigned long long pk3 = gload64(&gmax[(4 * j + 3) * 64 + b]);
                unsigned int c0 = 31u - ((unsigned int)pk0 & 31u);
                unsigned int c1 = 31u - ((unsigned int)pk1 & 31u);
                unsigned int c2 = 31u - ((unsigned int)pk2 & 31u);
                unsigned int c3 = 31u - ((unsigned int)pk3 & 31u);
                zcS[j][b] = c0 | (c1 << 8) | (c2 << 16) | (c3 << 24);
                if (blk == 0) {
                    int* zr = zidx + (t - 1) * 32 * NB;
                    zr[(4 * j + 0) * NB + b] = (int)c0;
                    zr[(4 * j + 1) * NB + b] = (int)c1;
                    zr[(4 * j + 2) * NB + b] = (int)c2;
                    zr[(4 * j + 3) * NB + b] = (int)c3;
                }
            }
            __syncthreads();
            // (2) split z/act gather: half = tid>>8 handles 16 groups x 3 gates
            {
                int half = tid >> 8, dd3 = (tid >> 6) & 3, bb3 = tid & 63;
                int d = d0 + dd3;
                float keep = keepT[t * NB + bb3];
#pragma unroll
                for (int g3 = 0; g3 < 3; ++g3) {
                    const float* Wrow = Wih + (size_t)(g3 * 1024 + d) * GIN;
                    float part = 0.f;
                    if (t > 0) {
                        float s = 0.f;
                        int gbase = half * 16;
#pragma unroll
                        for (int g = 0; g < 16; ++g) {
                            int gg = gbase + g;
                            int c = (int)((zcS[gg >> 2][bb3] >> ((gg & 3) * 8)) & 31u);
                            s += Wrow[gg * 32 + c];
                        }
                        part = keep * s;
                    }
                    if (half == 0) {
                        part += bih[g3 * 1024 + d];
#pragma unroll
                        for (int a = 0; a < NA; ++a)
                            part = fmaf(Wrow[ND + a], actT[(t * NA + a) * NB + bb3], part);
                    }
                    sGx2[half][g3][dd3][bb3] = part;
                }
            }
            __syncthreads();
            // (3) finalize gates + h_new
            if (tid < 256) {
                int d = d0 + dd;
                float keep = keepT[t * NB + bb];
                float gh0 = 0.f, gh1 = 0.f, gh2 = 0.f;
#pragma unroll
                for (int ww = 0; ww < 8; ++ww) {
                    gh0 += sRed[ww][dd + 0][bb];
                    gh1 += sRed[ww][dd + 4][bb];
                    gh2 += sRed[ww][dd + 8][bb];
                }
                float ghr = fmaf(keep, gh0, bhh[d]);
                float ghz = fmaf(keep, gh1, bhh[1024 + d]);
                float ghn = fmaf(keep, gh2, bhh[2048 + d]);
                float gxr = sGx2[0][0][dd][bb] + sGx2[1][0][dd][bb];
                float gxz = sGx2[0][1][dd][bb] + sGx2[1][1][dd][bb];
                float gxn = sGx2[0][2][dd][bb] + sGx2[1][2][dd][bb];
                float r = 1.f / (1.f + __expf(-(gxr + ghr)));
                float u = 1.f / (1.f + __expf(-(gxz + ghz)));
                float n = tanhf(gxn + r * ghn);
                float hprevm = 0.f;
                if (t > 0)
                    hprevm = keep * hhist[((size_t)(t - 1) * ND + d) * NB + bb];  // L2-warm
                sV[dd][bb] = (1.f - u) * n + u * hprevm;
            }
            __syncthreads();
            if (tid < 64) {   // vectorized bypass store: 4 rows x 16 float4
                int d2 = tid >> 4, bq = (tid & 15) * 4;
                f4v v = { sV[d2][bq], sV[d2][bq + 1], sV[d2][bq + 2], sV[d2][bq + 3] };
                gstore128(&hhist[((size_t)t * ND + d0 + d2) * NB + bq], v);
            }
        }
        // -------- S1 --------
        GRID_BARRIER();
        // -------- PHASE B: fused qw1·h[t] (for phT) + Whh·h[t] (for t+1) --------
        {
            const float* hrow = hhist + (size_t)t * ND * NB;   // normal (first touch fresh)
            float eprev = 0.f;
            if (tid < 256)   // issue bypass read early (hidden under FMA loop)
                eprev = gload(&epre[((size_t)t * NH + d0 + dd) * NB + bb]);
            float acc4[4] = {0.f, 0.f, 0.f, 0.f};
#pragma unroll
            for (int r = 0; r < 12; ++r) accP[r] = 0.f;
            int base = w * 128;
            for (int kt = 0; kt < 128; kt += 16) {
                float hbuf[16];
#pragma unroll
                for (int j = 0; j < 16; ++j)
                    hbuf[j] = hrow[(size_t)(base + kt + j) * NB + lane];
#pragma unroll
                for (int j4 = 0; j4 < 16; j4 += 4) {
                    int k = base + kt + j4;
#pragma unroll
                    for (int r = 0; r < 12; ++r) {
                        float4 wv = *(const float4*)&sWhh[r][k];   // LDS broadcast
                        accP[r] = fmaf(wv.x, hbuf[j4 + 0], accP[r]);
                        accP[r] = fmaf(wv.y, hbuf[j4 + 1], accP[r]);
                        accP[r] = fmaf(wv.z, hbuf[j4 + 2], accP[r]);
                        accP[r] = fmaf(wv.w, hbuf[j4 + 3], accP[r]);
                    }
#pragma unroll
                    for (int rr = 0; rr < 4; ++rr) {
                        float4 wv = *(const float4*)&sQw1[rr][k];  // LDS broadcast
                        acc4[rr] = fmaf(wv.x, hbuf[j4 + 0], acc4[rr]);
                        acc4[rr] = fmaf(wv.y, hbuf[j4 + 1], acc4[rr]);
                        acc4[rr] = fmaf(wv.z, hbuf[j4 + 2], acc4[rr]);
                        acc4[rr] = fmaf(wv.w, hbuf[j4 + 3], acc4[rr]);
                    }
                }
            }
#pragma unroll
            for (int rr = 0; rr < 4; ++rr) sRed[w][rr][lane] = acc4[rr];
            if (blk == 0 && tid >= 256) {   // reset argmax accumulators (waves 4-7)
                for (int i = tid - 256; i < 2048; i += 256) gstore64(&gmax[i], 0ull);
            }
            __syncthreads();
            if (tid < 256) {
                float s = 0.f;
#pragma unroll
                for (int ww = 0; ww < 8; ++ww) s += sRed[ww][dd][bb];
                sV[dd][bb] = s + qb1[d0 + dd] + eprev;
            }
            __syncthreads();
            if (tid < 64) {
                int d2 = tid >> 4, bq = (tid & 15) * 4;
                f4v v = { sV[d2][bq], sV[d2][bq + 1], sV[d2][bq + 2], sV[d2][bq + 3] };
                gstore128(&epre[((size_t)t * NH + d0 + d2) * NB + bq], v);
            }
        }
        // -------- S2 --------
        GRID_BARRIER();
        // ---------------- PHASE C: LN+SiLU+post w2 + argmax ----------------
        {
            const float* phTn = epre + (size_t)t * NH * NB;    // NORMAL reads (fresh lines)
            int base = w * 128;
            // pass 1: LN stats
            float s1 = 0.f, s2 = 0.f;
            for (int kt = 0; kt < 128; kt += 16) {
                float hbuf[16];
#pragma unroll
                for (int j = 0; j < 16; ++j)
                    hbuf[j] = phTn[(size_t)(base + kt + j) * NB + lane];
#pragma unroll
                for (int j = 0; j < 16; ++j) { s1 += hbuf[j]; s2 = fmaf(hbuf[j], hbuf[j], s2); }
            }
            sRed[w][0][lane] = s1; sRed[w][1][lane] = s2;
            __syncthreads();
            if (tid < 64) {
                float a = 0.f, q = 0.f;
#pragma unroll
                for (int ww = 0; ww < 8; ++ww) { a += sRed[ww][0][tid]; q += sRed[ww][1][tid]; }
                float mean = a * (1.f / NH);
                float var = q * (1.f / NH) - mean * mean;
                smean[tid] = mean;
                srstd[tid] = 1.f / sqrtf(var + EPS);
            }
            __syncthreads();
            float mean = smean[lane], rstd = srstd[lane];
            float acc4[4] = {0.f, 0.f, 0.f, 0.f};
            for (int kt = 0; kt < 128; kt += 16) {
                float hbuf[16];
#pragma unroll
                for (int j = 0; j < 16; ++j)
                    hbuf[j] = phTn[(size_t)(base + kt + j) * NB + lane];   // L2-hot re-read
#pragma unroll
                for (int j4 = 0; j4 < 16; j4 += 4) {
                    int k = base + kt + j4;
                    float4 gv = *(const float4*)&sQg[k];
                    float4 bv = *(const float4*)&sQbe[k];
                    float x0 = fmaf((hbuf[j4 + 0] - mean) * rstd, gv.x, bv.x);
                    float x1 = fmaf((hbuf[j4 + 1] - mean) * rstd, gv.y, bv.y);
                    float x2 = fmaf((hbuf[j4 + 2] - mean) * rstd, gv.z, bv.z);
                    float x3 = fmaf((hbuf[j4 + 3] - mean) * rstd, gv.w, bv.w);
                    float sl0 = x0 / (1.f + __expf(-x0));
                    float sl1 = x1 / (1.f + __expf(-x1));
                    float sl2 = x2 / (1.f + __expf(-x2));
                    float sl3 = x3 / (1.f + __expf(-x3));
#pragma unroll
                    for (int jj = 0; jj < 4; ++jj) {
                        float4 wv = *(const float4*)&sQw2[jj][k];  // LDS broadcast
                        acc4[jj] = fmaf(wv.x, sl0, acc4[jj]);
                        acc4[jj] = fmaf(wv.y, sl1, acc4[jj]);
                        acc4[jj] = fmaf(wv.z, sl2, acc4[jj]);
                        acc4[jj] = fmaf(wv.w, sl3, acc4[jj]);
                    }
                }
            }
#pragma unroll
            for (int jj = 0; jj < 4; ++jj) sRed[w][jj][lane] = acc4[jj];
            __syncthreads();
            if (tid < 256) {
                float s = 0.f;
#pragma unroll
                for (int ww = 0; ww < 8; ++ww) s += sRed[ww][dd][bb];
                float lg = s + qb2[d0 + dd];
                sV[dd][bb] = lg;
                unsigned bits = __float_as_uint(lg);
                unsigned key = (bits & 0x80000000u) ? ~bits : (bits | 0x80000000u);
                int cls = (d0 + dd) & 31;
                pkst[dd][bb] = ((unsigned long long)key << 32) | (unsigned long long)(31 - cls);
            }
            __syncthreads();
            if (tid < 64) {
                int d2 = tid >> 4, bq = (tid & 15) * 4;
                float4 v = { sV[d2][bq], sV[d2][bq + 1], sV[d2][bq + 2], sV[d2][bq + 3] };
                *(float4*)&lhist[((size_t)t * NSC + d0 + d2) * NB + bq] = v;  // normal store
                unsigned long long m = pkst[0][tid];
                if (pkst[1][tid] > m) m = pkst[1][tid];
                if (pkst[2][tid] > m) m = pkst[2][tid];
                if (pkst[3][tid] > m) m = pkst[3][tid];
                __hip_atomic_fetch_max(&gmax[(d0 >> 5) * 64 + tid], m,
                                       __ATOMIC_RELAXED, __HIP_MEMORY_SCOPE_AGENT);
            }
        }
        // -------- S3 --------
        GRID_BARRIER();
    }
    // final timestep's z indices for k4 (gmax final after S3(63))
    if (blk == 0) {
        int j = w, b = lane;
#pragma unroll
        for (int i = 0; i < 4; ++i) {
            unsigned long long pk = gload64(&gmax[(4 * j + i) * 64 + b]);
            zidx[63 * 32 * NB + (4 * j + i) * NB + b] = (int)(31u - ((unsigned int)pk & 31u));
        }
    }
#undef GRID_BARRIER
}

// =================== K3a: prior w1 + LN stats ===================
__global__ __launch_bounds__(256) void k3_p1(const float* __restrict__ w1p,
                                             const float* __restrict__ b1p,
                                             float* __restrict__ ws)
{
    int blk = blockIdx.x;
    int t = blk >> 6, kg = blk & 63, k0 = kg * 16;
    int tid = threadIdx.x, w = tid >> 6, lane = tid & 63;
    const float* hrow = ws + O_HHIST + (size_t)t * ND * NB;
    float acc[16];
#pragma unroll
    for (int i = 0; i < 16; ++i) acc[i] = 0.f;
    int dd0 = w * 256;
    for (int d = dd0; d < dd0 + 256; d += 4) {
        float hv0 = hrow[(size_t)(d + 0) * NB + lane];
        float hv1 = hrow[(size_t)(d + 1) * NB + lane];
        float hv2 = hrow[(size_t)(d + 2) * NB + lane];
        float hv3 = hrow[(size_t)(d + 3) * NB + lane];
#pragma unroll
        for (int kk = 0; kk < 16; ++kk) {
            float4 wv = *(const float4*)&w1p[(size_t)(k0 + kk) * ND + d];
            acc[kk] = fmaf(wv.x, hv0, acc[kk]);
            acc[kk] = fmaf(wv.y, hv1, acc[kk]);
            acc[kk] = fmaf(wv.z, hv2, acc[kk]);
            acc[kk] = fmaf(wv.w, hv3, acc[kk]);
        }
    }
    __shared__ float red[4][16][64];
    __shared__ float vst[16][64];
#pragma unroll
    for (int kk = 0; kk < 16; ++kk) red[w][kk][lane] = acc[kk];
    __syncthreads();
    float* ph1 = ws + O_EPRE + (size_t)t * NH * NB;  // reuse E_pre region
    for (int q = 0; q < 4; ++q) {
        int slot = tid + q * 256;
        int kk = slot >> 6, b = slot & 63;
        float v = red[0][kk][b] + red[1][kk][b] + red[2][kk][b] + red[3][kk][b] + b1p[k0 + kk];
        ph1[(size_t)(k0 + kk) * NB + b] = v;
        vst[kk][b] = v;
    }
    __syncthreads();
    if (tid < 64) {
        float s1 = 0.f, s2 = 0.f;
#pragma unroll
        for (int kk = 0; kk < 16; ++kk) { float v = vst[kk][tid]; s1 += v; s2 = fmaf(v, v, s2); }
        float* pst = ws + O_PSTAT;
        atomicAdd(&pst[(t * NB + tid) * 2 + 0], s1);
        atomicAdd(&pst[(t * NB + tid) * 2 + 1], s2);
    }
}

// =================== K3b: prior LN+SiLU+w2 -> prior_logits ===================
__global__ __launch_bounds__(256) void k3_p2(const float* __restrict__ gp,
                                             const float* __restrict__ bep,
                                             const float* __restrict__ w2p,
                                             const float* __restrict__ b2p,
                                             float* __restrict__ ws,
                                             float* __restrict__ out)
{
    int blk = blockIdx.x;
    int t = blk >> 6, jg = blk & 63, j0 = jg * 16;
    int tid = threadIdx.x, w = tid >> 6, lane = tid & 63;
    const float* ph1 = ws + O_EPRE + (size_t)t * NH * NB;
    const float* pst = ws + O_PSTAT;
    __shared__ float smean[64], srstd[64];
    if (tid < 64) {
        float s1 = pst[(t * NB + tid) * 2], s2 = pst[(t * NB + tid) * 2 + 1];
        float mean = s1 * (1.f / NH);
        float var = s2 * (1.f / NH) - mean * mean;
        smean[tid] = mean;
        srstd[tid] = 1.f / sqrtf(var + EPS);
    }
    __syncthreads();
    float mean = smean[lane], rstd = srstd[lane];
    float acc[16];
#pragma unroll
    for (int i = 0; i < 16; ++i) acc[i] = 0.f;
    int kk0 = w * 256;
    for (int k = kk0; k < kk0 + 256; k += 4) {
        float4 gv = *(const float4*)&gp[k];
        float4 bv = *(const float4*)&bep[k];
        float v0 = ph1[(size_t)(k + 0) * NB + lane];
        float v1 = ph1[(size_t)(k + 1) * NB + lane];
        float v2 = ph1[(size_t)(k + 2) * NB + lane];
        float v3 = ph1[(size_t)(k + 3) * NB + lane];
        float x0 = fmaf((v0 - mean) * rstd, gv.x, bv.x);
        float x1 = fmaf((v1 - mean) * rstd, gv.y, bv.y);
        float x2 = fmaf((v2 - mean) * rstd, gv.z, bv.z);
        float x3 = fmaf((v3 - mean) * rstd, gv.w, bv.w);
        float sl0 = x0 / (1.f + __expf(-x0));
        float sl1 = x1 / (1.f + __expf(-x1));
        float sl2 = x2 / (1.f + __expf(-x2));
        float sl3 = x3 / (1.f + __expf(-x3));
#pragma unroll
        for (int jj = 0; jj < 16; ++jj) {
            float4 wv = *(const float4*)&w2p[(size_t)(j0 + jj) * NH + k];
            acc[jj] = fmaf(wv.x, sl0, acc[jj]);
            acc[jj] = fmaf(wv.y, sl1, acc[jj]);
            acc[jj] = fmaf(wv.z, sl2, acc[jj]);
            acc[jj] = fmaf(wv.w, sl3, acc[jj]);
        }
    }
    __shared__ float red[4][16][64];
#pragma unroll
    for (int jj = 0; jj < 16; ++jj) red[w][jj][lane] = acc[jj];
    __syncthreads();
    float* prior = out + OUT_PRIOR;
    for (int q = 0; q < 4; ++q) {
        int slot = tid + q * 256;
        int b = slot >> 4, jj = slot & 15;
        float v = red[0][jj][b] + red[1][jj][b] + red[2][jj][b] + red[3][jj][b] + b2p[j0 + jj];
        prior[((size_t)b * NT + t) * NSC + j0 + jj] = v;
    }
}

// =================== K4: write-out transposes ===================
__global__ void k4_out(float* __restrict__ ws, float* __restrict__ out)
{
    int blk = blockIdx.x, tid = threadIdx.x;
    int rr = tid >> 6, ln = tid & 63;
    float* latent = out + OUT_LATENT;
    float* hseq = out + OUT_HSEQ;
    float* post = out + OUT_POST;
    if (blk < 1024) {
        int t = blk >> 4, dt = blk & 15, base_d = dt * 64;
        __shared__ float tile[64][65];
        const float* hh = ws + O_HHIST + (size_t)t * ND * NB;
        for (int q = 0; q < 16; ++q) {
            int row = q * 4 + rr;
            tile[row][ln] = hh[(size_t)(base_d + row) * NB + ln];
        }
        __syncthreads();
        for (int q = 0; q < 16; ++q) {
            int b = q * 4 + rr;
            float v = tile[ln][b];
            hseq[((size_t)b * NT + t) * ND + base_d + ln] = v;
            latent[((size_t)b * NT + t) * 2048 + base_d + ln] = v;
        }
    } else if (blk < 2048) {
        int bb = blk - 1024;
        int t = bb >> 4, jt = bb & 15, base_j = jt * 64;
        __shared__ float tile[64][65];
        const float* lh = ws + O_LHIST + (size_t)t * NSC * NB;
        for (int q = 0; q < 16; ++q) {
            int row = q * 4 + rr;
            tile[row][ln] = lh[(size_t)(base_j + row) * NB + ln];
        }
        __syncthreads();
        for (int q = 0; q < 16; ++q) {
            int b = q * 4 + rr;
            post[((size_t)b * NT + t) * NSC + base_j + ln] = tile[ln][b];
        }
    } else {
        int t = blk - 2048;
        const int* zi = (const int*)(ws + O_ZIDX) + t * 32 * NB;
        __shared__ int zl[32];
        for (int b = 0; b < NB; ++b) {
            if (tid < 32) zl[tid] = zi[tid * NB + b];
            __syncthreads();
            for (int q = 0; q < 4; ++q) {
                int j = q * 256 + tid;
                latent[((size_t)b * NT + t) * 2048 + 1024 + j] = (zl[j >> 5] == (j & 31)) ? 1.f : 0.f;
            }
            __syncthreads();
        }
    }
}

extern "C" void kernel_launch(void* const* d_in, const int* in_sizes, int n_in,
                              void* d_out, int out_size, void* d_ws, size_t ws_size,
                              hipStream_t stream)
{
    const float* embeds  = (const float*)d_in[0];
    const float* actions = (const float*)d_in[1];
    const int*   isfirst = (const int*)d_in[2];
    const float* Wih = (const float*)d_in[3];
    const float* Whh = (const float*)d_in[4];
    const float* bih = (const float*)d_in[5];
    const float* bhh = (const float*)d_in[6];
    const float* pw1r = (const float*)d_in[7];
    const float* pb1r = (const float*)d_in[8];
    const float* pgr  = (const float*)d_in[9];
    const float* pber = (const float*)d_in[10];
    const float* pw2r = (const float*)d_in[11];
    const float* pb2r = (const float*)d_in[12];
    const float* qw1 = (const float*)d_in[13];
    const float* qb1 = (const float*)d_in[14];
    const float* qg  = (const float*)d_in[15];
    const float* qbe = (const float*)d_in[16];
    const float* qw2 = (const float*)d_in[17];
    const float* qb2 = (const float*)d_in[18];
    float* out = (float*)d_out;
    float* ws = (float*)d_ws;

    hipLaunchKernelGGL(k0_prep, dim3(1538), dim3(256), 0, stream, embeds, actions, isfirst, ws);
    hipLaunchKernelGGL(k1_epre, dim3(4096), dim3(256), 0, stream, qw1, ws);

    void* args[] = {(void*)&Wih, (void*)&Whh, (void*)&bih, (void*)&bhh,
                    (void*)&qw1, (void*)&qb1, (void*)&qg, (void*)&qbe,
                    (void*)&qw2, (void*)&qb2, (void*)&ws};
    hipLaunchCooperativeKernel((void*)k2_scan, dim3(256), dim3(512), args, 0, stream);

    hipLaunchKernelGGL(k3_p1, dim3(4096), dim3(256), 0, stream, pw1r, pb1r, ws);
    hipLaunchKernelGGL(k3_p2, dim3(4096), dim3(256), 0, stream, pgr, pber, pw2r, pb2r, ws, out);
    hipLaunchKernelGGL(k4_out, dim3(2112), dim3(256), 0, stream, ws, out);
}